// Round 16
// baseline (215.204 us; speedup 1.0000x reference)
//
#include <hip/hip_runtime.h>
#include <stdint.h>

#define Hdim 112
#define Wdim 112
#define CIN  128
#define COUT 128
#define NB   32
#define HW   (Hdim*Wdim)   // 12544
#define HALO_W 66
#define HALO_PX (4*HALO_W)          // 264 pixels (4 rows x 66 cols)
#define SSTR (HALO_PX*16)           // 4224 B per ci-16 slot

// ws layout:
//   Wi8 : int8 [9][COUT][CIN]  @ 0        (147456 B)  weight signs as +-1
//   pkx : uint4[NB*HW]         @ 147456   (6.4 MB)    packed activation sign bits

typedef int   v4i __attribute__((ext_vector_type(4)));
typedef int  v16i __attribute__((ext_vector_type(16)));
typedef float v4f __attribute__((ext_vector_type(4)));

__global__ void pack_w_i8(const float* __restrict__ W, char* __restrict__ Wi8) {
    int t = blockIdx.x * blockDim.x + threadIdx.x;
    if (t >= COUT * 9) return;
    int co = t / 9, tap = t % 9;
    const float* wp = W + (size_t)co * CIN * 9 + tap;
    uint32_t* dst = (uint32_t*)(Wi8 + ((size_t)tap * COUT + co) * CIN);
    #pragma unroll
    for (int c4 = 0; c4 < 32; c4++) {
        uint32_t word = 0;
        #pragma unroll
        for (int j = 0; j < 4; j++) {
            uint32_t neg = __float_as_uint(wp[(size_t)(c4 * 4 + j) * 9]) >> 31;
            word |= (neg ? 0xFFu : 0x01u) << (8 * j);
        }
        dst[c4] = word;
    }
}

// each thread packs 4 consecutive pixels across all 128 channels.
// x is 205 MB single-use -> nontemporal loads keep it out of L2/L3.
__global__ __launch_bounds__(256) void pack_x_kernel(const float* __restrict__ x,
                                                     uint4* __restrict__ pkx) {
    int gid = blockIdx.x * blockDim.x + threadIdx.x;   // 0..100351
    int n = gid / (HW / 4);
    int p = (gid - n * (HW / 4)) * 4;
    const float* xp = x + (size_t)n * CIN * HW + p;
    uint32_t m[4][4] = {{0,0,0,0},{0,0,0,0},{0,0,0,0},{0,0,0,0}};
    #pragma unroll
    for (int c = 0; c < CIN; c++) {
        v4f v = __builtin_nontemporal_load(
            reinterpret_cast<const v4f*>(xp + (size_t)c * HW));
        int q = c >> 5, s = c & 31;
        m[0][q] |= (__float_as_uint(v.x) >> 31) << s;
        m[1][q] |= (__float_as_uint(v.y) >> 31) << s;
        m[2][q] |= (__float_as_uint(v.z) >> 31) << s;
        m[3][q] |= (__float_as_uint(v.w) >> 31) << s;
    }
    uint4* op = pkx + (size_t)n * HW + p;
    #pragma unroll
    for (int j = 0; j < 4; j++)
        op[j] = make_uint4(m[j][0], m[j][1], m[j][2], m[j][3]);
}

// spread low 4 bits into 4 bytes: bit=0 -> 0x01 (+1), bit=1 -> 0xFF (-1)
__device__ __forceinline__ uint32_t expand4(uint32_t b) {
    uint32_t s = ((b & 0xFu) * 0x00204081u) & 0x01010101u;
    return 0x01010101u ^ (s * 0xFEu);
}

// implicit-GEMM binconv via i8 MFMA — reuse_B=2 tiling + A-PREFETCH + lean regs.
// Lessons encoded: (R15) no-prefetch serializes on L2 latency regardless of
// occupancy; (R9/R15) never request more waves than the arch-reg budget —
// instead shrink the wave so 3/SIMD happen naturally under (256,2):
// acc 2ct x 2pt = 64 AGPR + ~100 arch ≈ 165 total.
// Block = 128co x (2 rows x 64 cols); wave = 64co x 64px; every ds_read_b128
// feeds 2 MFMAs (halves per-CU LDS issue vs R14). Full next-tap A prefetch.
// Col chunks 0-63 / 48-111; chunk 1 skips local cols <16 on store.
// Halo [slot][pixel][16B] conflict-free; OOB masked after expand -> exact
// zero padding. NT stores (keeps Wi8/pkx cache-resident; R13-proven).
__global__ __launch_bounds__(256, 2) void binconv_mfma(
    const uint4* __restrict__ pkx, const char* __restrict__ Wi8,
    const float* __restrict__ bias, float* __restrict__ out) {
    __shared__ uint4 halo4[8 * HALO_PX];    // 33792 B
    char* halo = (char*)halo4;

    int tid = threadIdx.x;
    int c0 = blockIdx.x ? 48 : 0;           // chunk origin
    int h0 = blockIdx.y * 2;
    int n  = blockIdx.z;

    // stage 4x66 halo: expand 128 sign bits -> 128 i8 (+-1, 0 if OOB)
    for (int i = tid; i < HALO_PX; i += 256) {
        int r = i / HALO_W, c = i - r * HALO_W;
        int h = h0 - 1 + r, w = c0 - 1 + c;
        bool valid = (h >= 0) && (h < Hdim) && (w >= 0) && (w < Wdim);
        uint32_t keep = valid ? 0xFFFFFFFFu : 0u;
        int hc = min(max(h, 0), Hdim - 1);
        int wc = min(max(w, 0), Wdim - 1);
        uint4 bits = pkx[(size_t)n * HW + hc * Wdim + wc];
        uint32_t src[4] = {bits.x, bits.y, bits.z, bits.w};
        #pragma unroll
        for (int s = 0; s < 8; s++) {       // slot s = ci 16s..16s+15
            uint32_t q = src[s >> 1] >> ((s & 1) * 16);
            uint4 ov;
            ov.x = expand4(q)       & keep;
            ov.y = expand4(q >> 4)  & keep;
            ov.z = expand4(q >> 8)  & keep;
            ov.w = expand4(q >> 12) & keep;
            *reinterpret_cast<uint4*>(&halo[s * SSTR + i * 16]) = ov;
        }
    }

    int wid = tid >> 6, l = tid & 63;
    int al = l & 31, ah = l >> 5;
    int ctbase = (wid & 1) * 64;            // wave's co half (2 ct of 32)
    int ptb    = (wid >> 1) * 2;            // wave's px half (2 pt of 32)

    // halo byte base at tap (0,0) for the wave's two px tiles
    int hb[2];
    #pragma unroll
    for (int pt = 0; pt < 2; pt++) {
        int P = (ptb + pt) * 32 + al;       // linear px in 2x64 tile
        int r = P >> 6, c = P & 63;
        hb[pt] = (r * HALO_W + c) * 16 + ah * SSTR;
    }

    const char* wA = Wi8 + ((size_t)ctbase + al) * CIN + ah * 16;

    v16i acc[2][2];
    #pragma unroll
    for (int ct = 0; ct < 2; ct++)
        #pragma unroll
        for (int pt = 0; pt < 2; pt++)
            #pragma unroll
            for (int i = 0; i < 16; i++) acc[ct][pt][i] = 0;

    // A fragments for tap 0 (ct=0: co+0, ct=1: co+32)
    v4i A[2][4];
    #pragma unroll
    for (int kk = 0; kk < 4; kk++) {
        A[0][kk] = *reinterpret_cast<const v4i*>(wA + kk * 32);
        A[1][kk] = *reinterpret_cast<const v4i*>(wA + 32 * CIN + kk * 32);
    }

    __syncthreads();

    #pragma unroll
    for (int tap = 0; tap < 9; tap++) {
        // prefetch next tap's A while this tap's MFMAs run
        v4i N[2][4];
        if (tap < 8) {
            const char* wt = wA + (size_t)(tap + 1) * COUT * CIN;
            #pragma unroll
            for (int kk = 0; kk < 4; kk++) {
                N[0][kk] = *reinterpret_cast<const v4i*>(wt + kk * 32);
                N[1][kk] = *reinterpret_cast<const v4i*>(wt + 32 * CIN + kk * 32);
            }
        }
        const int doff = ((tap / 3) * HALO_W + (tap % 3)) * 16;
        #pragma unroll
        for (int kk = 0; kk < 4; kk++) {
            int sb = kk * 2 * SSTR + doff;
            v4i b0 = *reinterpret_cast<const v4i*>(&halo[sb + hb[0]]);
            v4i b1 = *reinterpret_cast<const v4i*>(&halo[sb + hb[1]]);
            acc[0][0] = __builtin_amdgcn_mfma_i32_32x32x32_i8(A[0][kk], b0, acc[0][0], 0, 0, 0);
            acc[0][1] = __builtin_amdgcn_mfma_i32_32x32x32_i8(A[0][kk], b1, acc[0][1], 0, 0, 0);
            acc[1][0] = __builtin_amdgcn_mfma_i32_32x32x32_i8(A[1][kk], b0, acc[1][0], 0, 0, 0);
            acc[1][1] = __builtin_amdgcn_mfma_i32_32x32x32_i8(A[1][kk], b1, acc[1][1], 0, 0, 0);
        }
        if (tap < 8) {
            #pragma unroll
            for (int kk = 0; kk < 4; kk++) { A[0][kk] = N[0][kk]; A[1][kk] = N[1][kk]; }
        }
    }

    // epilogue: C col=lane&31 (pixel), row=(reg&3)+8*(reg>>2)+4*ah (co).
    // chunk 1 (c0=48) skips local cols <16 (already written by chunk 0).
    float* ob = out + (size_t)n * COUT * HW;
    #pragma unroll
    for (int ct = 0; ct < 2; ct++) {
        #pragma unroll
        for (int reg = 0; reg < 16; reg++) {
            int co = ctbase + ct * 32 + (reg & 3) + ((reg >> 2) << 3) + (ah << 2);
            float bv = bias[co];
            #pragma unroll
            for (int pt = 0; pt < 2; pt++) {
                int P = (ptb + pt) * 32 + al;
                int cl = P & 63;
                if (c0 == 0 || cl >= 16) {
                    size_t off = (size_t)co * HW + (size_t)(h0 + (P >> 6)) * Wdim + c0 + cl;
                    __builtin_nontemporal_store((float)acc[ct][pt][reg] + bv, &ob[off]);
                }
            }
        }
    }
}

extern "C" void kernel_launch(void* const* d_in, const int* in_sizes, int n_in,
                              void* d_out, int out_size, void* d_ws, size_t ws_size,
                              hipStream_t stream) {
    const float* x = (const float*)d_in[0];
    const float* W = (const float*)d_in[1];
    const float* b = (const float*)d_in[2];
    float* out = (float*)d_out;
    char* ws = (char*)d_ws;
    char*  Wi8 = ws;
    uint4* pkx = (uint4*)(ws + 147456);

    pack_w_i8<<<dim3((COUT * 9 + 255) / 256), dim3(256), 0, stream>>>(W, Wi8);
    pack_x_kernel<<<dim3(NB * HW / 4 / 256), dim3(256), 0, stream>>>(x, pkx);
    binconv_mfma<<<dim3(2, Hdim / 2, NB), dim3(256), 0, stream>>>(pkx, Wi8, b, out);
}

// Round 17
// 128.523 us; speedup vs baseline: 1.6744x; 1.6744x over previous
//
#include <hip/hip_runtime.h>
#include <stdint.h>

#define Hdim 112
#define Wdim 112
#define CIN  128
#define COUT 128
#define NB   32
#define HW   (Hdim*Wdim)   // 12544
#define HALO_W 114
#define HALO_PX (4*HALO_W)         // 456 pixels (4 rows x 114 cols)
#define SLOT_STRIDE (HALO_PX*16)   // 7296 B per ci-16 slot

// ws layout:
//   Wi8 : int8 [9][COUT][CIN]  @ 0        (147456 B)  weight signs as +-1
//   pkx : uint4[NB*HW]         @ 147456   (6.4 MB)    packed activation sign bits

typedef int   v4i __attribute__((ext_vector_type(4)));
typedef int  v16i __attribute__((ext_vector_type(16)));
typedef float v4f __attribute__((ext_vector_type(4)));

__global__ void pack_w_i8(const float* __restrict__ W, char* __restrict__ Wi8) {
    int t = blockIdx.x * blockDim.x + threadIdx.x;
    if (t >= COUT * 9) return;
    int co = t / 9, tap = t % 9;
    const float* wp = W + (size_t)co * CIN * 9 + tap;
    uint32_t* dst = (uint32_t*)(Wi8 + ((size_t)tap * COUT + co) * CIN);
    #pragma unroll
    for (int c4 = 0; c4 < 32; c4++) {
        uint32_t word = 0;
        #pragma unroll
        for (int j = 0; j < 4; j++) {
            uint32_t neg = __float_as_uint(wp[(size_t)(c4 * 4 + j) * 9]) >> 31;
            word |= (neg ? 0xFFu : 0x01u) << (8 * j);
        }
        dst[c4] = word;
    }
}

// each thread packs 4 consecutive pixels across all 128 channels.
// x is 205 MB single-use -> nontemporal loads keep it out of L2/L3.
__global__ __launch_bounds__(256) void pack_x_kernel(const float* __restrict__ x,
                                                     uint4* __restrict__ pkx) {
    int gid = blockIdx.x * blockDim.x + threadIdx.x;   // 0..100351
    int n = gid / (HW / 4);
    int p = (gid - n * (HW / 4)) * 4;
    const float* xp = x + (size_t)n * CIN * HW + p;
    uint32_t m[4][4] = {{0,0,0,0},{0,0,0,0},{0,0,0,0},{0,0,0,0}};
    #pragma unroll
    for (int c = 0; c < CIN; c++) {
        v4f v = __builtin_nontemporal_load(
            reinterpret_cast<const v4f*>(xp + (size_t)c * HW));
        int q = c >> 5, s = c & 31;
        m[0][q] |= (__float_as_uint(v.x) >> 31) << s;
        m[1][q] |= (__float_as_uint(v.y) >> 31) << s;
        m[2][q] |= (__float_as_uint(v.z) >> 31) << s;
        m[3][q] |= (__float_as_uint(v.w) >> 31) << s;
    }
    uint4* op = pkx + (size_t)n * HW + p;
    #pragma unroll
    for (int j = 0; j < 4; j++)
        op[j] = make_uint4(m[j][0], m[j][1], m[j][2], m[j][3]);
}

// spread low 4 bits into 4 bytes: bit=0 -> 0x01 (+1), bit=1 -> 0xFF (-1)
__device__ __forceinline__ uint32_t expand4(uint32_t b) {
    uint32_t s = ((b & 0xFu) * 0x00204081u) & 0x01010101u;
    return 0x01010101u ^ (s * 0xFEu);
}

// implicit-GEMM binconv via i8 MFMA — R14 compute + LDS-TRANSPOSED WIDE STORES.
// R14 (proven ~83us): full-width 2-row tiles, wave = 32co x 224px, acc 7xv16i
// (112 AGPR), next-tap A prefetch (compiler honors this footprint: VGPR 128).
// New: epilogue transposes acc through the (dead) halo LDS so each lane NT-
// stores float4 -> 896B contiguous runs per (co,row-pair) instead of R14's
// 112 scalar stores in 128B segments (write rate was ~2.5 of 6.9 TB/s).
// Per wave: private 7296B slice, 4 rounds x {write 28 f32, read 8x float4,
// 8 NT dwordx4}. One extra barrier isolates epilogue writes from other
// waves' halo reads. OOB masked after expand -> exact zero padding.
__global__ __launch_bounds__(256, 2) void binconv_mfma(
    const uint4* __restrict__ pkx, const char* __restrict__ Wi8,
    const float* __restrict__ bias, float* __restrict__ out) {
    __shared__ char halo[8 * SLOT_STRIDE];   // 58368 B (halo, then transpose buf)

    int tid = threadIdx.x;
    int hy = blockIdx.x;                     // row-pair 0..55
    int n  = blockIdx.y;
    int h0 = hy * 2;

    // stage 4x114 halo: expand 128 sign bits -> 128 i8 (+-1, 0 if OOB)
    for (int i = tid; i < HALO_PX; i += 256) {
        int r = i / HALO_W, c = i - r * HALO_W;
        int h = h0 - 1 + r, w = c - 1;
        bool valid = (h >= 0) && (h < Hdim) && (w >= 0) && (w < Wdim);
        uint32_t keep = valid ? 0xFFFFFFFFu : 0u;
        int hc = min(max(h, 0), Hdim - 1);
        int wc = min(max(w, 0), Wdim - 1);
        uint4 bits = pkx[(size_t)n * HW + hc * Wdim + wc];
        uint32_t src[4] = {bits.x, bits.y, bits.z, bits.w};
        #pragma unroll
        for (int s = 0; s < 8; s++) {        // slot s = ci 16s..16s+15
            uint32_t q = src[s >> 1] >> ((s & 1) * 16);
            uint4 ov;
            ov.x = expand4(q)       & keep;
            ov.y = expand4(q >> 4)  & keep;
            ov.z = expand4(q >> 8)  & keep;
            ov.w = expand4(q >> 12) & keep;
            *reinterpret_cast<uint4*>(&halo[s * SLOT_STRIDE + i * 16]) = ov;
        }
    }

    int wid = tid >> 6, l = tid & 63;
    int al = l & 31, ah = l >> 5;
    int cobase = wid * 32;                   // wave's 32-co slice

    // per-pt halo byte base at tap (0,0): pixel P = pt*32+al of 2x112 tile
    int hb[7];
    #pragma unroll
    for (int pt = 0; pt < 7; pt++) {
        int P = pt * 32 + al;
        int r = (P >= Wdim) ? 1 : 0;
        int w = P - r * Wdim;
        hb[pt] = (r * HALO_W + w) * 16 + ah * SLOT_STRIDE;
    }

    const char* wA = Wi8 + ((size_t)cobase + al) * CIN + ah * 16;

    v16i acc[7];
    #pragma unroll
    for (int pt = 0; pt < 7; pt++)
        #pragma unroll
        for (int i = 0; i < 16; i++) acc[pt][i] = 0;

    // A fragments for tap 0
    v4i A[4];
    #pragma unroll
    for (int kk = 0; kk < 4; kk++)
        A[kk] = *reinterpret_cast<const v4i*>(wA + kk * 32);

    __syncthreads();

    #pragma unroll
    for (int tap = 0; tap < 9; tap++) {
        // prefetch next tap's A while this tap's MFMAs run
        v4i N[4];
        if (tap < 8) {
            const char* wt = wA + (size_t)(tap + 1) * COUT * CIN;
            #pragma unroll
            for (int kk = 0; kk < 4; kk++)
                N[kk] = *reinterpret_cast<const v4i*>(wt + kk * 32);
        }
        const int dy = tap / 3, dx = tap % 3;
        const int imm = (dy * HALO_W + dx) * 16;   // constant per tap
        #pragma unroll
        for (int kk = 0; kk < 4; kk++) {
            const int simm = imm + kk * 2 * SLOT_STRIDE;   // + ah via hb[]
            v4i b[7];
            #pragma unroll
            for (int pt = 0; pt < 7; pt++)
                b[pt] = *reinterpret_cast<const v4i*>(&halo[hb[pt] + simm]);
            #pragma unroll
            for (int pt = 0; pt < 7; pt++)
                acc[pt] = __builtin_amdgcn_mfma_i32_32x32x32_i8(A[kk], b[pt], acc[pt], 0, 0, 0);
        }
        if (tap < 8) {
            #pragma unroll
            for (int kk = 0; kk < 4; kk++) A[kk] = N[kk];
        }
    }

    // all waves done reading halo before we overwrite it as transpose buffer
    __syncthreads();

    // transposed wide-store epilogue.
    // acc C layout: col=lane&31 -> px = pt*32+al; row=(reg&3)+8*(reg>>2)+4*ah
    // -> co_local = j + 8q + 4ah for reg = 4q+j.
    // Round q: stage co_local 8q..8q+7 (225.. use stride 228 floats) in the
    // wave's private 7296B slice, then each of 56 lanes reads float4 =
    // 4 consecutive w of one (co,row) and NT-stores.
    {
        char* tb = halo + wid * 7296;
        int row = l / 28;                    // 0..1 (lanes 0..55)
        int wq  = l % 28;
        bool act = (l < 56);
        float* ob = out + (size_t)n * COUT * HW + (size_t)h0 * Wdim;
        #pragma unroll
        for (int q = 0; q < 4; q++) {
            #pragma unroll
            for (int j = 0; j < 4; j++) {
                int reg = q * 4 + j;
                int cl8 = j + 4 * ah;        // 0..7 slot within round
                float bv = bias[cobase + 8 * q + cl8];
                #pragma unroll
                for (int pt = 0; pt < 7; pt++) {
                    int px = pt * 32 + al;
                    *reinterpret_cast<float*>(&tb[(cl8 * 228 + px) * 4]) =
                        (float)acc[pt][reg] + bv;
                }
            }
            __builtin_amdgcn_s_waitcnt(0);   // lgkmcnt(0): writes visible to own lane reads
            #pragma unroll
            for (int cc = 0; cc < 8; cc++) {
                v4f val = *reinterpret_cast<v4f*>(&tb[(cc * 228 + row * Wdim + wq * 4) * 4]);
                if (act) {
                    int co = cobase + 8 * q + cc;
                    __builtin_nontemporal_store(val,
                        reinterpret_cast<v4f*>(&ob[(size_t)co * HW + row * Wdim + wq * 4]));
                }
            }
        }
    }
}

extern "C" void kernel_launch(void* const* d_in, const int* in_sizes, int n_in,
                              void* d_out, int out_size, void* d_ws, size_t ws_size,
                              hipStream_t stream) {
    const float* x = (const float*)d_in[0];
    const float* W = (const float*)d_in[1];
    const float* b = (const float*)d_in[2];
    float* out = (float*)d_out;
    char* ws = (char*)d_ws;
    char*  Wi8 = ws;
    uint4* pkx = (uint4*)(ws + 147456);

    pack_w_i8<<<dim3((COUT * 9 + 255) / 256), dim3(256), 0, stream>>>(W, Wi8);
    pack_x_kernel<<<dim3(NB * HW / 4 / 256), dim3(256), 0, stream>>>(x, pkx);
    binconv_mfma<<<dim3(Hdim / 2, NB), dim3(256), 0, stream>>>(pkx, Wi8, b, out);
}